// Round 7
// baseline (260.510 us; speedup 1.0000x reference)
//
#include <hip/hip_runtime.h>
#include <hip/hip_cooperative_groups.h>
#include <math.h>

namespace cg = cooperative_groups;

#define NH  16
#define SEQ 256
#define HD  64
#define HID 1024
#define N3  3072

// ws layout (float offsets; bf16 regions hold 2 shorts per float slot)
#define OFF_QB   0        // q  bf16 [H][S][D]
#define OFF_KB   131072   // k  bf16 [H][S][D]
#define OFF_KTB  262144   // kt bf16 [H][D][S]
#define OFF_VTB  393216   // vt bf16 [H][D][S]
#define OFF_CTX  524288   // ctx fp32 [S][HID]

typedef __attribute__((ext_vector_type(8))) short bf16x8;
typedef __attribute__((ext_vector_type(4))) float f32x4;
typedef __attribute__((ext_vector_type(4))) unsigned short us4;
typedef __attribute__((ext_vector_type(8))) unsigned short us8;

__device__ __forceinline__ unsigned short f2bf(float x) {
  unsigned u = __builtin_bit_cast(unsigned, x);
  u += 0x7FFF + ((u >> 16) & 1);  // RNE
  return (unsigned short)(u >> 16);
}
__device__ __forceinline__ float bf2f(unsigned short b) {
  return __builtin_bit_cast(float, (unsigned)b << 16);
}

// Single cooperative kernel: 256 blocks x 256 thr (1 block/CU, co-resident).
// Phase A: QKV GEMM (bf16 MFMA) + scatter   [blocks 0..191; 192..195 zero imp]
// Phase B: flash attention + closed-form qk_importance  [all 256 blocks]
// Phase C: dense GEMM + bias + residual     [blocks 0..127]
// Shared-memory arena: max(phaseA 10.2 KB, phaseB 45.3 KB, phaseC 7.5 KB).
__global__ __launch_bounds__(256) void k_fused(
    const float* __restrict__ A, const float* __restrict__ W,
    const float* __restrict__ bias, const float* __restrict__ alibi,
    const float* __restrict__ Wd, const float* __restrict__ bd,
    const float* __restrict__ resid, float* __restrict__ ws,
    float* __restrict__ out) {
  cg::grid_group grid = cg::this_grid();
  __shared__ __align__(16) char smem[45312];
  const int bid = blockIdx.x;
  const int tid = threadIdx.x;
  const int w = tid >> 6, lane = tid & 63;
  const int col = lane & 15, quad = lane >> 4;
  unsigned short* qb  = (unsigned short*)(ws + OFF_QB);
  unsigned short* kb  = (unsigned short*)(ws + OFF_KB);
  unsigned short* ktb = (unsigned short*)(ws + OFF_KTB);
  unsigned short* vtb = (unsigned short*)(ws + OFF_VTB);
  float* ctx = ws + OFF_CTX;

  // ============ Phase A: C[256x3072] = hidden @ Wqkv + bqkv ============
  if (bid < 192) {
    unsigned short* As = (unsigned short*)smem;       // 64*40 shorts
    unsigned short* Bs = As + 64 * 40;                // 64*40 shorts
    const int m0 = (bid / 48) * 64, n0 = (bid % 48) * 64;
    const int am = tid >> 3, ak = (tid & 7) * 4;
    const int bkg = w * 8;
    const float* Wp = W + n0 + lane;
    float4 a0 = *(const float4*)&A[(m0 + am) * HID + ak];
    float4 a1 = *(const float4*)&A[(m0 + 32 + am) * HID + ak];
    float pb[8];
#pragma unroll
    for (int u = 0; u < 8; ++u) pb[u] = Wp[(bkg + u) * N3];
    f32x4 acc[4] = {{0.f, 0.f, 0.f, 0.f}, {0.f, 0.f, 0.f, 0.f},
                    {0.f, 0.f, 0.f, 0.f}, {0.f, 0.f, 0.f, 0.f}};
    const int k8 = quad * 8;
    for (int k0 = 0; k0 < HID; k0 += 32) {
      *(us4*)&As[am * 40 + ak] =
          (us4){f2bf(a0.x), f2bf(a0.y), f2bf(a0.z), f2bf(a0.w)};
      *(us4*)&As[(am + 32) * 40 + ak] =
          (us4){f2bf(a1.x), f2bf(a1.y), f2bf(a1.z), f2bf(a1.w)};
      us8 bp;
#pragma unroll
      for (int u = 0; u < 8; ++u) bp[u] = f2bf(pb[u]);
      *(us8*)&Bs[lane * 40 + bkg] = bp;
      __syncthreads();
      const int kn = k0 + 32;
      if (kn < HID) {
        a0 = *(const float4*)&A[(m0 + am) * HID + kn + ak];
        a1 = *(const float4*)&A[(m0 + 32 + am) * HID + kn + ak];
#pragma unroll
        for (int u = 0; u < 8; ++u) pb[u] = Wp[(kn + bkg + u) * N3];
      }
      const bf16x8 af = *(const bf16x8*)&As[(w * 16 + col) * 40 + k8];
#pragma unroll
      for (int t = 0; t < 4; ++t) {
        const bf16x8 bf = *(const bf16x8*)&Bs[(t * 16 + col) * 40 + k8];
        acc[t] = __builtin_amdgcn_mfma_f32_16x16x32_bf16(af, bf, acc[t], 0, 0, 0);
      }
      __syncthreads();
    }
#pragma unroll
    for (int t = 0; t < 4; ++t) {
      const int n = n0 + t * 16 + col;
      const int h = n / 192;
      const int r2 = n - h * 192;
      const int which = r2 >> 6, d = r2 & 63;
      const float bv = bias[n];
#pragma unroll
      for (int r = 0; r < 4; ++r) {
        const int m = m0 + w * 16 + quad * 4 + r;
        const unsigned short vb = f2bf(acc[t][r] + bv);
        if (which == 0) {
          qb[(h * SEQ + m) * HD + d] = vb;
        } else if (which == 1) {
          kb[(h * SEQ + m) * HD + d] = vb;
          ktb[(h * HD + d) * SEQ + m] = vb;
        } else {
          vtb[(h * HD + d) * SEQ + m] = vb;
        }
      }
    }
  } else if (bid < 196) {
    out[SEQ * HID + (bid - 192) * 256 + tid] = 0.f;
  }
  __threadfence();
  grid.sync();

  // ============ Phase B: flash attention + qk_importance ============
  {
    const int h = bid >> 4, i0 = (bid & 15) * 16;
    unsigned short* Albs = (unsigned short*)smem;       // 3*16*280 shorts
    float* plds  = (float*)(smem + 26880);              // 16*260 floats
    float* redm  = (float*)(smem + 43520);              // 16*4
    float* reds  = (float*)(smem + 43776);              // 16*4
    float* red4  = (float*)(smem + 44032);              // 16*4*4
    float* rowsc = (float*)(smem + 45056);              // 16*4
    const unsigned short* qbh  = qb + h * SEQ * HD;
    const unsigned short* kbh  = kb + h * SEQ * HD;
    const unsigned short* ktbh = ktb + h * HD * SEQ;
    const unsigned short* vtbh = vtb + h * HD * SEQ;
    // ---- QK^T ----
    const bf16x8 a0 = *(const bf16x8*)&qbh[(i0 + col) * HD + quad * 8];
    const bf16x8 a1 = *(const bf16x8*)&qbh[(i0 + col) * HD + quad * 8 + 32];
    f32x4 acc[4] = {{0.f, 0.f, 0.f, 0.f}, {0.f, 0.f, 0.f, 0.f},
                    {0.f, 0.f, 0.f, 0.f}, {0.f, 0.f, 0.f, 0.f}};
#pragma unroll
    for (int t = 0; t < 4; ++t) {
      const int j = w * 64 + t * 16 + col;
      const bf16x8 b0 = *(const bf16x8*)&kbh[j * HD + quad * 8];
      const bf16x8 b1 = *(const bf16x8*)&kbh[j * HD + quad * 8 + 32];
      acc[t] = __builtin_amdgcn_mfma_f32_16x16x32_bf16(a0, b0, acc[t], 0, 0, 0);
      acc[t] = __builtin_amdgcn_mfma_f32_16x16x32_bf16(a1, b1, acc[t], 0, 0, 0);
    }
    // ---- scores, E = exp(base), row max ----
    float c[4][4], eb[4][4];
    float rmax[4] = {-3.0e38f, -3.0e38f, -3.0e38f, -3.0e38f};
#pragma unroll
    for (int t = 0; t < 4; ++t) {
      const int j = w * 64 + t * 16 + col;
      const float al = alibi[h * SEQ + j];
#pragma unroll
      for (int r = 0; r < 4; ++r) {
        const int i = i0 + quad * 4 + r;
        const float s = acc[t][r] * 0.125f;
        const float mv = (j <= i) ? 0.f : -1e9f;
        eb[t][r] = __expf((s + mv) * 0.125f);
        const float cv = al + s + mv;
        c[t][r] = cv;
        rmax[r] = fmaxf(rmax[r], cv);
      }
    }
#pragma unroll
    for (int r = 0; r < 4; ++r)
#pragma unroll
      for (int off = 1; off < 16; off <<= 1)
        rmax[r] = fmaxf(rmax[r], __shfl_xor(rmax[r], off));
    if (col == 0)
#pragma unroll
      for (int r = 0; r < 4; ++r) redm[(quad * 4 + r) * 4 + w] = rmax[r];
    __syncthreads();
    // ---- exp(c - M), row sum ----
    float rsum[4];
#pragma unroll
    for (int r = 0; r < 4; ++r) {
      const float4 m4 = *(const float4*)&redm[(quad * 4 + r) * 4];
      const float M = fmaxf(fmaxf(m4.x, m4.y), fmaxf(m4.z, m4.w));
      float s = 0.f;
#pragma unroll
      for (int t = 0; t < 4; ++t) {
        c[t][r] = __expf(c[t][r] - M);
        s += c[t][r];
      }
#pragma unroll
      for (int off = 1; off < 16; off <<= 1) s += __shfl_xor(s, off);
      rsum[r] = s;
    }
    if (col == 0)
#pragma unroll
      for (int r = 0; r < 4; ++r) reds[(quad * 4 + r) * 4 + w] = rsum[r];
    __syncthreads();
    // ---- normalize p, stage P + {E,E²,Ep}, row scalars ----
#pragma unroll
    for (int r = 0; r < 4; ++r) {
      const float4 s4 = *(const float4*)&reds[(quad * 4 + r) * 4];
      const float inv = __builtin_amdgcn_rcpf((s4.x + s4.y) + (s4.z + s4.w));
      const int il = quad * 4 + r;
      float s0 = 0.f, t0 = 0.f, u0 = 0.f, sp = 0.f;
#pragma unroll
      for (int t = 0; t < 4; ++t) {
        const int j = w * 64 + t * 16 + col;
        const float p = c[t][r] * inv;
        const float E = eb[t][r];
        plds[il * 260 + j] = p;
        Albs[il * 280 + j] = f2bf(E);
        Albs[16 * 280 + il * 280 + j] = f2bf(E * E);
        Albs[2 * 16 * 280 + il * 280 + j] = f2bf(E * p);
        s0 += E;
        t0 = __builtin_fmaf(E, E, t0);
        u0 = __builtin_fmaf(E, p, u0);
        sp = __builtin_fmaf(p, p, sp);
      }
#pragma unroll
      for (int off = 1; off < 16; off <<= 1) {
        s0 += __shfl_xor(s0, off);
        t0 += __shfl_xor(t0, off);
        u0 += __shfl_xor(u0, off);
        sp += __shfl_xor(sp, off);
      }
      if (col == 0)
        *(float4*)&red4[(il * 4 + w) * 4] = (float4){s0, t0, u0, sp};
    }
    __syncthreads();
    if (tid < 64) {
      const int row = tid >> 2, x = tid & 3;
      rowsc[row * 4 + x] = (red4[(row * 4 + 0) * 4 + x] + red4[(row * 4 + 1) * 4 + x]) +
                           (red4[(row * 4 + 2) * 4 + x] + red4[(row * 4 + 3) * 4 + x]);
    }
    __syncthreads();
    // ---- PV: wave w -> d = w*16..w*16+15 ----
    f32x4 o = {0.f, 0.f, 0.f, 0.f};
#pragma unroll
    for (int s = 0; s < 8; ++s) {
      const int kk = quad * 8 + s * 32;
      const float4 pa = *(const float4*)&plds[col * 260 + kk];
      const float4 pc = *(const float4*)&plds[col * 260 + kk + 4];
      const us8 af = {f2bf(pa.x), f2bf(pa.y), f2bf(pa.z), f2bf(pa.w),
                      f2bf(pc.x), f2bf(pc.y), f2bf(pc.z), f2bf(pc.w)};
      const bf16x8 vb = *(const bf16x8*)&vtbh[(w * 16 + col) * SEQ + kk];
      o = __builtin_amdgcn_mfma_f32_16x16x32_bf16(
          __builtin_bit_cast(bf16x8, af), vb, o, 0, 0, 0);
    }
#pragma unroll
    for (int r = 0; r < 4; ++r)
      ctx[(i0 + quad * 4 + r) * HID + h * HD + w * 16 + col] = o[r];
    // ---- moment matmuls {E,E²,Ep} @ [K | K∘K] ----
    f32x4 m6[3][2] = {{{0.f, 0.f, 0.f, 0.f}, {0.f, 0.f, 0.f, 0.f}},
                      {{0.f, 0.f, 0.f, 0.f}, {0.f, 0.f, 0.f, 0.f}},
                      {{0.f, 0.f, 0.f, 0.f}, {0.f, 0.f, 0.f, 0.f}}};
    const unsigned short* ktrow = ktbh + (w * 16 + col) * SEQ;
#pragma unroll
    for (int s = 0; s < 8; ++s) {
      const int kk = quad * 8 + s * 32;
      const bf16x8 kb8 = *(const bf16x8*)&ktrow[kk];
      us8 kq;
#pragma unroll
      for (int u = 0; u < 8; ++u) {
        const float t = bf2f((unsigned short)kb8[u]);
        kq[u] = f2bf(t * t);
      }
      const bf16x8 k2 = __builtin_bit_cast(bf16x8, kq);
#pragma unroll
      for (int lhs = 0; lhs < 3; ++lhs) {
        const bf16x8 af = *(const bf16x8*)&Albs[lhs * 16 * 280 + col * 280 + kk];
        m6[lhs][0] = __builtin_amdgcn_mfma_f32_16x16x32_bf16(af, kb8, m6[lhs][0], 0, 0, 0);
        m6[lhs][1] = __builtin_amdgcn_mfma_f32_16x16x32_bf16(af, k2, m6[lhs][1], 0, 0, 0);
      }
    }
    // ---- closed-form eval + reduce (2nd-order delta expansion) ----
    const int dg = w * 16 + col;
    float racc = 0.f;
#pragma unroll
    for (int r = 0; r < 4; ++r) {
      const int il = quad * 4 + r;
      const float qc = -0.015625f * bf2f(qbh[(i0 + il) * HD + dg]);
      const float s0 = rowsc[il * 4 + 0], t0 = rowsc[il * 4 + 1];
      const float u0 = rowsc[il * 4 + 2], sp = rowsc[il * 4 + 3];
      const float S1 = __builtin_fmaf(
          qc, __builtin_fmaf(0.5f * qc, m6[0][1][r], m6[0][0][r]), s0);
      const float S2 = __builtin_fmaf(
          2.f * qc, __builtin_fmaf(qc, m6[1][1][r], m6[1][0][r]), t0);
      const float S3 = __builtin_fmaf(
          qc, __builtin_fmaf(0.5f * qc, m6[2][1][r], m6[2][0][r]), u0);
      const float inv = __builtin_amdgcn_rcpf(S1);
      racc += __builtin_fmaf(__builtin_fmaf(S2, inv, -2.f * S3), inv, sp);
    }
    racc += __shfl_xor(racc, 16);
    racc += __shfl_xor(racc, 32);
    if (lane < 16) atomicAdd(&out[SEQ * HID + h * HD + w * 16 + lane], racc);
  }
  __threadfence();
  grid.sync();

  // ============ Phase C: out = ctx @ Wd + bd + resid ============
  if (bid < 128) {
    unsigned short* As = (unsigned short*)smem;        // 32*40 shorts
    unsigned short* Bs = As + 32 * 40;                 // 64*40 shorts
    const int m0 = (bid >> 4) * 32, n0 = (bid & 15) * 64;
    const int am = tid >> 3, ak = (tid & 7) * 4;
    const int bkg = w * 8;
    const float* Wp = Wd + n0 + lane;
    float4 a0 = *(const float4*)&ctx[(m0 + am) * HID + ak];
    float pb[8];
#pragma unroll
    for (int u = 0; u < 8; ++u) pb[u] = Wp[(bkg + u) * HID];
    f32x4 acc[2] = {{0.f, 0.f, 0.f, 0.f}, {0.f, 0.f, 0.f, 0.f}};
    const int k8 = quad * 8;
    const int mt = w & 1, nh = w >> 1;
    for (int k0 = 0; k0 < HID; k0 += 32) {
      *(us4*)&As[am * 40 + ak] =
          (us4){f2bf(a0.x), f2bf(a0.y), f2bf(a0.z), f2bf(a0.w)};
      us8 bp;
#pragma unroll
      for (int u = 0; u < 8; ++u) bp[u] = f2bf(pb[u]);
      *(us8*)&Bs[lane * 40 + bkg] = bp;
      __syncthreads();
      const int kn = k0 + 32;
      if (kn < HID) {
        a0 = *(const float4*)&ctx[(m0 + am) * HID + kn + ak];
#pragma unroll
        for (int u = 0; u < 8; ++u) pb[u] = Wp[(kn + bkg + u) * HID];
      }
      const bf16x8 af = *(const bf16x8*)&As[(mt * 16 + col) * 40 + k8];
#pragma unroll
      for (int t = 0; t < 2; ++t) {
        const bf16x8 bf =
            *(const bf16x8*)&Bs[(nh * 32 + t * 16 + col) * 40 + k8];
        acc[t] = __builtin_amdgcn_mfma_f32_16x16x32_bf16(af, bf, acc[t], 0, 0, 0);
      }
      __syncthreads();
    }
#pragma unroll
    for (int t = 0; t < 2; ++t) {
      const int n = n0 + nh * 32 + t * 16 + col;
      const float bv = bd[n];
#pragma unroll
      for (int r = 0; r < 4; ++r) {
        const int m = m0 + mt * 16 + quad * 4 + r;
        out[m * HID + n] = acc[t][r] + bv + resid[m * HID + n];
      }
    }
  }
}

extern "C" void kernel_launch(void* const* d_in, const int* in_sizes, int n_in,
                              void* d_out, int out_size, void* d_ws,
                              size_t ws_size, hipStream_t stream) {
  const float* hidden   = (const float*)d_in[0];
  const float* residual = (const float*)d_in[1];
  const float* alibi    = (const float*)d_in[2];
  const float* Wqkv     = (const float*)d_in[4];
  const float* bqkv     = (const float*)d_in[5];
  const float* Wd       = (const float*)d_in[6];
  const float* bd       = (const float*)d_in[7];
  float* out = (float*)d_out;
  float* ws  = (float*)d_ws;

  void* args[] = {(void*)&hidden, (void*)&Wqkv, (void*)&bqkv, (void*)&alibi,
                  (void*)&Wd, (void*)&bd, (void*)&residual, (void*)&ws,
                  (void*)&out};
  hipLaunchCooperativeKernel((void*)k_fused, dim3(256), dim3(256), args, 0,
                             stream);
}

// Round 9
// 124.658 us; speedup vs baseline: 2.0898x; 2.0898x over previous
//
#include <hip/hip_runtime.h>
#include <math.h>

#define NH  16
#define SEQ 256
#define HD  64
#define HID 1024
#define N3  3072

// ws layout (float offsets; bf16 regions hold 2 shorts per float slot)
#define OFF_QB   0        // q  bf16 [H][S][D]
#define OFF_KB   131072   // k  bf16 [H][S][D]
#define OFF_KTB  262144   // kt bf16 [H][D][S]
#define OFF_VTB  393216   // vt bf16 [H][D][S]
#define OFF_CTX  524288   // ctx fp32 [S][HID]

typedef __attribute__((ext_vector_type(8))) short bf16x8;
typedef __attribute__((ext_vector_type(4))) float f32x4;
typedef __attribute__((ext_vector_type(2))) unsigned short us2;
typedef __attribute__((ext_vector_type(4))) unsigned short us4;
typedef __attribute__((ext_vector_type(8))) unsigned short us8;

__device__ __forceinline__ unsigned short f2bf(float x) {
  unsigned u = __builtin_bit_cast(unsigned, x);
  u += 0x7FFF + ((u >> 16) & 1);  // RNE
  return (unsigned short)(u >> 16);
}
__device__ __forceinline__ float bf2f(unsigned short b) {
  return __builtin_bit_cast(float, (unsigned)b << 16);
}

// ---------------- K1: fused QKV GEMM (bf16 MFMA) + scatter -------------------
// C[256x3072] = hidden @ Wqkv + bqkv.  BM=32 BN=64 BK=32, 256 thr,
// grid (48,8) = 384 blocks (~1.5/CU).  Wave w: row-tile w&1, col-half w>>1.
// R8 bug fixed: V scatter must be vt[h][d][s] = [(h*HD+d)*SEQ+m].
__global__ __launch_bounds__(256) void k_qkv(
    const float* __restrict__ A, const float* __restrict__ W,
    const float* __restrict__ bias, float* __restrict__ ws,
    float* __restrict__ out) {
  if (blockIdx.x == 0 && blockIdx.y < 4)
    out[SEQ * HID + blockIdx.y * 256 + threadIdx.x] = 0.f;
  __shared__ __align__(16) unsigned short As[32 * 40];
  __shared__ __align__(16) unsigned short Bs[64 * 40];
  const int tid = threadIdx.x;
  const int w = tid >> 6, lane = tid & 63;
  const int col = lane & 15, quad = lane >> 4;
  const int m0 = blockIdx.y * 32, n0 = blockIdx.x * 64;
  const int am = tid >> 3, ak = (tid & 7) * 4;
  const int bkg = w * 8;
  const float* Wp = W + n0 + lane;
  float4 a0 = *(const float4*)&A[(m0 + am) * HID + ak];
  float pb[8];
#pragma unroll
  for (int u = 0; u < 8; ++u) pb[u] = Wp[(bkg + u) * N3];
  f32x4 acc[2] = {{0.f, 0.f, 0.f, 0.f}, {0.f, 0.f, 0.f, 0.f}};
  const int k8 = quad * 8;
  const int mt = w & 1, nh = w >> 1;
  for (int k0 = 0; k0 < HID; k0 += 32) {
    *(us4*)&As[am * 40 + ak] =
        (us4){f2bf(a0.x), f2bf(a0.y), f2bf(a0.z), f2bf(a0.w)};
    us8 bp;
#pragma unroll
    for (int u = 0; u < 8; ++u) bp[u] = f2bf(pb[u]);
    *(us8*)&Bs[lane * 40 + bkg] = bp;
    __syncthreads();
    const int kn = k0 + 32;
    if (kn < HID) {
      a0 = *(const float4*)&A[(m0 + am) * HID + kn + ak];
#pragma unroll
      for (int u = 0; u < 8; ++u) pb[u] = Wp[(kn + bkg + u) * N3];
    }
    const bf16x8 af = *(const bf16x8*)&As[(mt * 16 + col) * 40 + k8];
#pragma unroll
    for (int t = 0; t < 2; ++t) {
      const bf16x8 bf =
          *(const bf16x8*)&Bs[(nh * 32 + t * 16 + col) * 40 + k8];
      acc[t] = __builtin_amdgcn_mfma_f32_16x16x32_bf16(af, bf, acc[t], 0, 0, 0);
    }
    __syncthreads();
  }
  unsigned short* qb  = (unsigned short*)(ws + OFF_QB);
  unsigned short* kb  = (unsigned short*)(ws + OFF_KB);
  unsigned short* ktb = (unsigned short*)(ws + OFF_KTB);
  unsigned short* vtb = (unsigned short*)(ws + OFF_VTB);
#pragma unroll
  for (int t = 0; t < 2; ++t) {
    const int n = n0 + nh * 32 + t * 16 + col;
    const int h = n / 192;
    const int r2 = n - h * 192;
    const int which = r2 >> 6, d = r2 & 63;
    const float bv = bias[n];
#pragma unroll
    for (int r = 0; r < 4; ++r) {
      const int m = m0 + mt * 16 + quad * 4 + r;
      const unsigned short vb = f2bf(acc[t][r] + bv);
      if (which == 0) {
        qb[(h * SEQ + m) * HD + d] = vb;
      } else if (which == 1) {
        kb[(h * SEQ + m) * HD + d] = vb;
        ktb[(h * HD + d) * SEQ + m] = vb;
      } else {
        vtb[(h * HD + d) * SEQ + m] = vb;  // vt [h][d][s]  (R8 bug was [h][s][d])
      }
    }
  }
}

// ---------------- K2: MFMA flash attention + fused qk_importance -------------
// (unchanged from R6: block = (h, 16 rows), moment-matmul closed form)
__global__ __launch_bounds__(256) void k_attn(
    const float* __restrict__ alibi, float* __restrict__ ws,
    float* __restrict__ out) {
  const int bx = blockIdx.x;
  const int h = bx >> 4, i0 = (bx & 15) * 16;
  const int tid = threadIdx.x, w = tid >> 6, lane = tid & 63;
  const int col = lane & 15, quad = lane >> 4;
  __shared__ __align__(16) unsigned short Albs[3 * 16 * 280];  // 26.9 KB
  __shared__ __align__(16) float plds[16 * 260];               // 16.6 KB
  __shared__ __align__(16) float redm[16][4];
  __shared__ __align__(16) float reds[16][4];
  __shared__ __align__(16) float red4[16][4][4];
  __shared__ __align__(16) float rowsc[16][4];
  const unsigned short* qbh  = (const unsigned short*)(ws + OFF_QB) + h * SEQ * HD;
  const unsigned short* kbh  = (const unsigned short*)(ws + OFF_KB) + h * SEQ * HD;
  const unsigned short* ktbh = (const unsigned short*)(ws + OFF_KTB) + h * HD * SEQ;
  const unsigned short* vtbh = (const unsigned short*)(ws + OFF_VTB) + h * HD * SEQ;
  // ---- QK^T ----
  const bf16x8 a0 = *(const bf16x8*)&qbh[(i0 + col) * HD + quad * 8];
  const bf16x8 a1 = *(const bf16x8*)&qbh[(i0 + col) * HD + quad * 8 + 32];
  f32x4 acc[4] = {{0.f, 0.f, 0.f, 0.f}, {0.f, 0.f, 0.f, 0.f},
                  {0.f, 0.f, 0.f, 0.f}, {0.f, 0.f, 0.f, 0.f}};
#pragma unroll
  for (int t = 0; t < 4; ++t) {
    const int j = w * 64 + t * 16 + col;
    const bf16x8 b0 = *(const bf16x8*)&kbh[j * HD + quad * 8];
    const bf16x8 b1 = *(const bf16x8*)&kbh[j * HD + quad * 8 + 32];
    acc[t] = __builtin_amdgcn_mfma_f32_16x16x32_bf16(a0, b0, acc[t], 0, 0, 0);
    acc[t] = __builtin_amdgcn_mfma_f32_16x16x32_bf16(a1, b1, acc[t], 0, 0, 0);
  }
  // ---- scores, E = exp(base), row max ----
  float c[4][4], eb[4][4];
  float rmax[4] = {-3.0e38f, -3.0e38f, -3.0e38f, -3.0e38f};
#pragma unroll
  for (int t = 0; t < 4; ++t) {
    const int j = w * 64 + t * 16 + col;
    const float al = alibi[h * SEQ + j];
#pragma unroll
    for (int r = 0; r < 4; ++r) {
      const int i = i0 + quad * 4 + r;
      const float s = acc[t][r] * 0.125f;
      const float mv = (j <= i) ? 0.f : -1e9f;
      eb[t][r] = __expf((s + mv) * 0.125f);
      const float cv = al + s + mv;
      c[t][r] = cv;
      rmax[r] = fmaxf(rmax[r], cv);
    }
  }
#pragma unroll
  for (int r = 0; r < 4; ++r)
#pragma unroll
    for (int off = 1; off < 16; off <<= 1)
      rmax[r] = fmaxf(rmax[r], __shfl_xor(rmax[r], off));
  if (col == 0)
#pragma unroll
    for (int r = 0; r < 4; ++r) redm[quad * 4 + r][w] = rmax[r];
  __syncthreads();
  // ---- exp(c - M), row sum ----
  float rsum[4];
#pragma unroll
  for (int r = 0; r < 4; ++r) {
    const float4 m4 = *(const float4*)redm[quad * 4 + r];
    const float M = fmaxf(fmaxf(m4.x, m4.y), fmaxf(m4.z, m4.w));
    float s = 0.f;
#pragma unroll
    for (int t = 0; t < 4; ++t) {
      c[t][r] = __expf(c[t][r] - M);
      s += c[t][r];
    }
#pragma unroll
    for (int off = 1; off < 16; off <<= 1) s += __shfl_xor(s, off);
    rsum[r] = s;
  }
  if (col == 0)
#pragma unroll
    for (int r = 0; r < 4; ++r) reds[quad * 4 + r][w] = rsum[r];
  __syncthreads();
  // ---- normalize p, stage P + {E,E²,Ep}, row scalars ----
#pragma unroll
  for (int r = 0; r < 4; ++r) {
    const float4 s4 = *(const float4*)reds[quad * 4 + r];
    const float inv = __builtin_amdgcn_rcpf((s4.x + s4.y) + (s4.z + s4.w));
    const int il = quad * 4 + r;
    float s0 = 0.f, t0 = 0.f, u0 = 0.f, sp = 0.f;
#pragma unroll
    for (int t = 0; t < 4; ++t) {
      const int j = w * 64 + t * 16 + col;
      const float p = c[t][r] * inv;
      const float E = eb[t][r];
      plds[il * 260 + j] = p;
      Albs[il * 280 + j] = f2bf(E);
      Albs[16 * 280 + il * 280 + j] = f2bf(E * E);
      Albs[2 * 16 * 280 + il * 280 + j] = f2bf(E * p);
      s0 += E;
      t0 = __builtin_fmaf(E, E, t0);
      u0 = __builtin_fmaf(E, p, u0);
      sp = __builtin_fmaf(p, p, sp);
    }
#pragma unroll
    for (int off = 1; off < 16; off <<= 1) {
      s0 += __shfl_xor(s0, off);
      t0 += __shfl_xor(t0, off);
      u0 += __shfl_xor(u0, off);
      sp += __shfl_xor(sp, off);
    }
    if (col == 0) *(float4*)&red4[il][w][0] = (float4){s0, t0, u0, sp};
  }
  __syncthreads();
  if (tid < 64) {
    const int row = tid >> 2, x = tid & 3;
    rowsc[row][x] = (red4[row][0][x] + red4[row][1][x]) +
                    (red4[row][2][x] + red4[row][3][x]);
  }
  __syncthreads();
  // ---- PV: wave w -> d = w*16..w*16+15 ----
  f32x4 o = {0.f, 0.f, 0.f, 0.f};
#pragma unroll
  for (int s = 0; s < 8; ++s) {
    const int kk = quad * 8 + s * 32;
    const float4 pa = *(const float4*)&plds[col * 260 + kk];
    const float4 pc = *(const float4*)&plds[col * 260 + kk + 4];
    const us8 af = {f2bf(pa.x), f2bf(pa.y), f2bf(pa.z), f2bf(pa.w),
                    f2bf(pc.x), f2bf(pc.y), f2bf(pc.z), f2bf(pc.w)};
    const bf16x8 vb = *(const bf16x8*)&vtbh[(w * 16 + col) * SEQ + kk];
    o = __builtin_amdgcn_mfma_f32_16x16x32_bf16(
        __builtin_bit_cast(bf16x8, af), vb, o, 0, 0, 0);
  }
  float* ctx = ws + OFF_CTX;
#pragma unroll
  for (int r = 0; r < 4; ++r)
    ctx[(i0 + quad * 4 + r) * HID + h * HD + w * 16 + col] = o[r];
  // ---- moment matmuls {E,E²,Ep} @ [K | K∘K] ----
  f32x4 m6[3][2] = {{{0.f, 0.f, 0.f, 0.f}, {0.f, 0.f, 0.f, 0.f}},
                    {{0.f, 0.f, 0.f, 0.f}, {0.f, 0.f, 0.f, 0.f}},
                    {{0.f, 0.f, 0.f, 0.f}, {0.f, 0.f, 0.f, 0.f}}};
  const unsigned short* ktrow = ktbh + (w * 16 + col) * SEQ;
#pragma unroll
  for (int s = 0; s < 8; ++s) {
    const int kk = quad * 8 + s * 32;
    const bf16x8 kb8 = *(const bf16x8*)&ktrow[kk];
    us8 kq;
#pragma unroll
    for (int u = 0; u < 8; ++u) {
      const float t = bf2f((unsigned short)kb8[u]);
      kq[u] = f2bf(t * t);
    }
    const bf16x8 k2 = __builtin_bit_cast(bf16x8, kq);
#pragma unroll
    for (int lhs = 0; lhs < 3; ++lhs) {
      const bf16x8 af = *(const bf16x8*)&Albs[lhs * 16 * 280 + col * 280 + kk];
      m6[lhs][0] = __builtin_amdgcn_mfma_f32_16x16x32_bf16(af, kb8, m6[lhs][0], 0, 0, 0);
      m6[lhs][1] = __builtin_amdgcn_mfma_f32_16x16x32_bf16(af, k2, m6[lhs][1], 0, 0, 0);
    }
  }
  // ---- closed-form eval + reduce (2nd-order delta expansion) ----
  const int dg = w * 16 + col;
  float racc = 0.f;
#pragma unroll
  for (int r = 0; r < 4; ++r) {
    const int il = quad * 4 + r;
    const float qc = -0.015625f * bf2f(qbh[(i0 + il) * HD + dg]);
    const float s0 = rowsc[il][0], t0 = rowsc[il][1];
    const float u0 = rowsc[il][2], sp = rowsc[il][3];
    const float S1 = __builtin_fmaf(
        qc, __builtin_fmaf(0.5f * qc, m6[0][1][r], m6[0][0][r]), s0);
    const float S2 = __builtin_fmaf(
        2.f * qc, __builtin_fmaf(qc, m6[1][1][r], m6[1][0][r]), t0);
    const float S3 = __builtin_fmaf(
        qc, __builtin_fmaf(0.5f * qc, m6[2][1][r], m6[2][0][r]), u0);
    const float inv = __builtin_amdgcn_rcpf(S1);
    racc += __builtin_fmaf(__builtin_fmaf(S2, inv, -2.f * S3), inv, sp);
  }
  racc += __shfl_xor(racc, 16);
  racc += __shfl_xor(racc, 32);
  if (lane < 16) atomicAdd(&out[SEQ * HID + h * HD + w * 16 + lane], racc);
}

// ---------------- K3: dense GEMM (bf16 MFMA) + bias + residual ---------------
// BM=16 BN=64 BK=32, 256 thr, grid (16,16) = 256 blocks.
__global__ __launch_bounds__(256) void k_dense(
    const float* __restrict__ W, const float* __restrict__ bias,
    const float* __restrict__ resid, float* __restrict__ out,
    const float* __restrict__ ws) {
  __shared__ __align__(16) unsigned short As[16 * 40];
  __shared__ __align__(16) unsigned short Bs[64 * 40];
  const int tid = threadIdx.x;
  const int w = tid >> 6, lane = tid & 63;
  const int col = lane & 15, quad = lane >> 4;
  const int m0 = blockIdx.y * 16, n0 = blockIdx.x * 64;
  const int am = tid >> 4, ak = (tid & 15) * 2;
  const int bkg = w * 8;
  const float* A = ws + OFF_CTX;
  const float* Wp = W + n0 + lane;
  float2 a0 = *(const float2*)&A[(m0 + am) * HID + ak];
  float pb[8];
#pragma unroll
  for (int u = 0; u < 8; ++u) pb[u] = Wp[(bkg + u) * HID];
  f32x4 acc = {0.f, 0.f, 0.f, 0.f};
  const int k8 = quad * 8;
  for (int k0 = 0; k0 < HID; k0 += 32) {
    *(us2*)&As[am * 40 + ak] = (us2){f2bf(a0.x), f2bf(a0.y)};
    us8 bp;
#pragma unroll
    for (int u = 0; u < 8; ++u) bp[u] = f2bf(pb[u]);
    *(us8*)&Bs[lane * 40 + bkg] = bp;
    __syncthreads();
    const int kn = k0 + 32;
    if (kn < HID) {
      a0 = *(const float2*)&A[(m0 + am) * HID + kn + ak];
#pragma unroll
      for (int u = 0; u < 8; ++u) pb[u] = Wp[(kn + bkg + u) * HID];
    }
    const bf16x8 af = *(const bf16x8*)&As[col * 40 + k8];
    const bf16x8 bf = *(const bf16x8*)&Bs[(w * 16 + col) * 40 + k8];
    acc = __builtin_amdgcn_mfma_f32_16x16x32_bf16(af, bf, acc, 0, 0, 0);
    __syncthreads();
  }
  const int n = n0 + w * 16 + col;
  const float bv = bias[n];
#pragma unroll
  for (int r = 0; r < 4; ++r) {
    const int m = m0 + quad * 4 + r;
    out[m * HID + n] = acc[r] + bv + resid[m * HID + n];
  }
}

extern "C" void kernel_launch(void* const* d_in, const int* in_sizes, int n_in,
                              void* d_out, int out_size, void* d_ws,
                              size_t ws_size, hipStream_t stream) {
  const float* hidden   = (const float*)d_in[0];
  const float* residual = (const float*)d_in[1];
  const float* alibi    = (const float*)d_in[2];
  const float* Wqkv     = (const float*)d_in[4];
  const float* bqkv     = (const float*)d_in[5];
  const float* Wd       = (const float*)d_in[6];
  const float* bd       = (const float*)d_in[7];
  float* out = (float*)d_out;
  float* ws  = (float*)d_ws;

  k_qkv<<<dim3(48, 8), 256, 0, stream>>>(hidden, Wqkv, bqkv, ws, out);
  k_attn<<<dim3(256), 256, 0, stream>>>(alibi, ws, out);
  k_dense<<<dim3(16, 16), 256, 0, stream>>>(Wd, bd, residual, out, ws);
}